// Round 1
// baseline (228.208 us; speedup 1.0000x reference)
//
#include <hip/hip_runtime.h>
#include <math.h>

// NeuralstackOnly, 5-stage decomposition (R6: stack_kernel occupancy split):
//  K1: g[b,t]   = elu(cos(latch_enable, x[b,t,:]))   wave-per-t, float4
//  K2: latch scan -> L[b,t,:]                         chunked load batching
//  K3: pop[b,t] = elu(cos(should_pop, L[b,t,:]))      wave-per-t, float4
//  K4: pointer recurrence -> P[b,t,32]                reg-prefetched pops
//  K5: stack recurrence + readout                     single-wave blocks,
//      R6: 8 dsub x 8 ng (4 slots each), grid (D/8,B) = 4096 blocks
//      -> 4 waves/SIMD (was 2). Coefficients still recomputed from P
//      (1xb128/t — LDS-coeff variant would be LDS-pipe-bound at 16 w/CU).
// B=128, T=256, D=256, NSTK=32.

#define NSTK 32
#define DDIM 256
#define ZO 1e-6f
#define EPSC 1e-8f
#define PEPS 1e-12f
#define TTILE 32
#define MAXT 1024

__device__ __forceinline__ float elu_f(float c) {
    return (c > 0.f) ? c : expm1f(c);
}

// DPP cross-lane helpers (sum-reduce pairings within groups of 32) — verified R4
__device__ __forceinline__ float dpp_xor1(float x) {   // quad_perm [1,0,3,2]
    return __int_as_float(__builtin_amdgcn_update_dpp(0, __float_as_int(x), 0xB1, 0xF, 0xF, true));
}
__device__ __forceinline__ float dpp_xor2(float x) {   // quad_perm [2,3,0,1]
    return __int_as_float(__builtin_amdgcn_update_dpp(0, __float_as_int(x), 0x4E, 0xF, 0xF, true));
}
__device__ __forceinline__ float dpp_halfmirror(float x) {  // row_half_mirror
    return __int_as_float(__builtin_amdgcn_update_dpp(0, __float_as_int(x), 0x141, 0xF, 0xF, true));
}
__device__ __forceinline__ float dpp_mirror(float x) {      // row_mirror
    return __int_as_float(__builtin_amdgcn_update_dpp(0, __float_as_int(x), 0x140, 0xF, 0xF, true));
}
__device__ __forceinline__ float swz_xor16(float x) {  // lane ^= 16 within 32
    return __int_as_float(__builtin_amdgcn_ds_swizzle(__float_as_int(x), 0x401F));
}

// ---------------- K1 / K3: wave-per-t cosine gate ---------------------------
__global__ void gate4_kernel(const float* __restrict__ vecs,   // [B,T,D]
                             const float* __restrict__ par,    // [D]
                             float* __restrict__ gout,         // [B,T]
                             int T) {
    const int b = blockIdx.y;
    const int t = blockIdx.x * 4 + (threadIdx.x >> 6);
    const int lane = threadIdx.x & 63;
    const float4 v = *(const float4*)(vecs + ((size_t)b * T + t) * DDIM + lane * 4);
    const float4 p = *(const float4*)(par + lane * 4);
    float r0 = v.x * p.x + v.y * p.y + v.z * p.z + v.w * p.w;
    float r1 = v.x * v.x + v.y * v.y + v.z * v.z + v.w * v.w;
    float r2 = p.x * p.x + p.y * p.y + p.z * p.z + p.w * p.w;
#pragma unroll
    for (int off = 32; off >= 1; off >>= 1) {
        r0 += __shfl_xor(r0, off, 64);
        r1 += __shfl_xor(r1, off, 64);
        r2 += __shfl_xor(r2, off, 64);
    }
    if (lane == 0) {
        const float c = r0 / (fmaxf(sqrtf(r2), EPSC) * fmaxf(sqrtf(r1), EPSC));
        gout[(size_t)b * T + t] = elu_f(c);
    }
}

// ---------------- K2: latch scan, chunked load batching ---------------------
__global__ void latch_scan_kernel(const float* __restrict__ x,       // [B,T,D]
                                  const float* __restrict__ latch0,  // [B,D]
                                  const float* __restrict__ g,       // [B,T]
                                  float* __restrict__ L,             // [B,T,D]
                                  int T) {
    const int b = blockIdx.x >> 2;
    const int dt = blockIdx.x & 3;
    const int d = dt * 64 + threadIdx.x;
    const float* xb = x + (size_t)b * T * DDIM + d;
    const float* gb = g + (size_t)b * T;
    float* Lb = L + (size_t)b * T * DDIM + d;
    float l = latch0[(size_t)b * DDIM + d];
    for (int c = 0; c < T; c += 32) {
        float xv[32], gv[32];
#pragma unroll
        for (int i = 0; i < 32; i++) xv[i] = xb[(size_t)(c + i) * DDIM];
#pragma unroll
        for (int i = 0; i < 32; i++) gv[i] = gb[c + i];
#pragma unroll
        for (int i = 0; i < 32; i++) {
            Lb[(size_t)(c + i) * DDIM] = l;           // latch ENTERING step c+i
            l = fmaf(gv[i], xv[i] - l, l);
        }
    }
}

// ---------------- K4: pointer recurrence, 2 b per wave ----------------------
// Emits P[b,t,32] = normalized sharpened pointer AFTER step t (t=0..T-1).
__launch_bounds__(64, 1)
__global__ void ptr_scan_kernel(const float* __restrict__ pop_arr,  // [B,T]
                                const float* __restrict__ sharpen_ptr,
                                float* __restrict__ Parr,           // [B,T,32]
                                int T) {
    const int b0 = blockIdx.x * 2;
    const int tid = threadIdx.x;
    const int n = tid & 31;
    const int grp = tid >> 5;                  // 0/1 -> which b
    const float sharpen = sharpen_ptr[0];
    const bool sharp5 = (sharpen == 5.0f);

    __shared__ float pops[2 * MAXT];
    for (int i = tid; i < 2 * T; i += 64) pops[i] = pop_arr[(size_t)b0 * T + i];
    __syncthreads();
    const float* popg = pops + grp * T;
    float* Pb = Parr + (size_t)(b0 + grp) * T * 32;

    float u = (n == 0) ? 1.0f : ZO;    // unnormalized pointer entering step t
    float invu = 1.0f;                 // its normalizer (p = u * invu)
    int t = 0;

    auto step = [&](float pop) {
        const float push = 1.0f - pop;
        const float up = __shfl(u, (n + 31) & 31, 32);   // roll +1
        const float un = __shfl(u, (n + 1) & 31, 32);    // roll -1
        const float r = fmaf(push, up, pop * un);
        const float q = fmaxf(r * invu, PEPS);
        float unew;
        if (sharp5) { const float q2 = q * q, q4 = q2 * q2; unew = q4 * q; }
        else        { unew = exp2f(sharpen * log2f(q)); }
        float s = unew;
        s += dpp_xor1(s);
        s += dpp_xor2(s);
        s += dpp_halfmirror(s);
        s += dpp_mirror(s);
        s += swz_xor16(s);
        const float invn = 1.0f / fmaxf(s, EPSC);
        Pb[(size_t)t * 32 + n] = unew * invn;
        u = unew; invu = invn;
        t++;
    };

    const float4* p4 = (const float4*)popg;
    float4 cA0 = p4[0], cA1 = p4[1], cA2 = p4[2], cA3 = p4[3];
    for (int c = 0; c < T; c += 16) {
        float4 cB0, cB1, cB2, cB3;
        if (c + 16 < T) {
            const float4* pn4 = p4 + (c + 16) / 4;
            cB0 = pn4[0]; cB1 = pn4[1]; cB2 = pn4[2]; cB3 = pn4[3];
        }
        step(cA0.x); step(cA0.y); step(cA0.z); step(cA0.w);
        step(cA1.x); step(cA1.y); step(cA1.z); step(cA1.w);
        step(cA2.x); step(cA2.y); step(cA2.z); step(cA2.w);
        step(cA3.x); step(cA3.y); step(cA3.z); step(cA3.w);
        if (c + 16 < T) { cA0 = cB0; cA1 = cB1; cA2 = cB2; cA3 = cB3; }
    }
}

// ---------------- K5: stack recurrence + readout ----------------------------
// R6: Single-wave blocks, grid (D/8, B). Lane = 8 dsub x 8 ng (4 slots each).
// 4096 blocks -> 16 waves/CU = 4 waves/SIMD (was 2; VALUBusy was 43%).
// Coefficients recomputed from P: alpha = 1 - push*pp - pop*p, beta = push*pp,
// gamma = ZO*pop*p, w = pop*P[t+1] (pop factored out of the readout sum).
__launch_bounds__(64, 1)
__global__ void stack_kernel(const float* __restrict__ x,       // [B,T,D]
                             const float* __restrict__ Parr,    // [B,T,32]
                             const float* __restrict__ pop_arr, // [B,T]
                             float* __restrict__ out,           // [B,T,D]
                             int T) {
    const int b = blockIdx.y;
    const int dtile = blockIdx.x;              // 0..31
    const int lane = threadIdx.x;              // 0..63
    const int dsub = lane & 7;
    const int ng = lane >> 3;                  // slots ng*4..ng*4+3

    __shared__ float Ps[TTILE * 32];           // 4 KB
    __shared__ float xs[TTILE * 8];            // 1 KB
    __shared__ float ps[TTILE];                // 128 B

    const float* Pb = Parr + (size_t)b * T * 32;
    const float* xtb = x + (size_t)b * T * DDIM + dtile * 8;
    const float* popb = pop_arr + (size_t)b * T;
    float* ob = out + (size_t)b * T * DDIM + dtile * 8 + dsub;

    float4 Preg0, Preg1, Preg2, Preg3, xreg0, popreg;
    const int xr0 = lane >> 1, xc0 = (lane & 1) * 4;   // 32 t-rows x 8 d

    auto load_regs = [&](int t0) {
        const float4* P4 = (const float4*)(Pb + (size_t)t0 * 32);
        Preg0 = P4[lane];
        Preg1 = P4[lane + 64];
        Preg2 = P4[lane + 128];
        Preg3 = P4[lane + 192];
        xreg0 = *(const float4*)(xtb + (size_t)(t0 + xr0) * DDIM + xc0);
        if (lane < 8) popreg = *(const float4*)(popb + t0 + lane * 4);
    };
    auto store_lds = [&]() {
        ((float4*)Ps)[lane] = Preg0;
        ((float4*)Ps)[lane + 64] = Preg1;
        ((float4*)Ps)[lane + 128] = Preg2;
        ((float4*)Ps)[lane + 192] = Preg3;
        ((float4*)xs)[lane] = xreg0;
        if (lane < 8) ((float4*)ps)[lane] = popreg;
    };

    float st[4], pc[4];
#pragma unroll
    for (int i = 0; i < 4; i++) { st[i] = ZO; pc[i] = ZO; }
    if (ng == 0) pc[0] = 1.0f;                 // P[0] one-hot at slot 0

    load_regs(0);
    store_lds();

    const int NT = T / TTILE;
    for (int tile = 0; tile < NT; tile++) {
        if (tile + 1 < NT) load_regs((tile + 1) * TTILE);   // global -> regs
        const int tg0 = tile * TTILE;
#pragma unroll 4
        for (int tl = 0; tl < TTILE; tl++) {
            const float pop = ps[tl];
            const float push = 1.0f - pop;
            const float4 pn0 = *(const float4*)(Ps + tl * 32 + ng * 4);
            const float xv = xs[tl * 8 + dsub];
            // slot ng*4-1 (wrap) = previous group's last element
            const float pm1 = __shfl(pc[3], ((ng + 7) & 7) * 8 + dsub, 64);
            const float pn[4] = {pn0.x, pn0.y, pn0.z, pn0.w};
            float acc = 0.f;
#pragma unroll
            for (int i = 0; i < 4; i++) {
                const float p_s = pc[i];
                const float pp_s = (i == 0) ? pm1 : pc[i - 1];
                const float t0v = pop * p_s;
                const float m = fmaf(push, pp_s, t0v);
                const float alpha = 1.0f - m;
                const float beta = push * pp_s;
                const float bxg = fmaf(beta, xv, ZO * t0v);
                const float ns = fmaf(alpha, st[i], bxg);
                st[i] = ns;
                acc = fmaf(pn[i], ns, acc);    // w = pop*pn, pop factored out
            }
#pragma unroll
            for (int i = 0; i < 4; i++) pc[i] = pn[i];
            acc += __shfl_xor(acc, 8, 64);
            acc += __shfl_xor(acc, 16, 64);
            acc += __shfl_xor(acc, 32, 64);
            if (ng == 0) ob[(size_t)(tg0 + tl) * DDIM] = pop * acc;
        }
        // per-wave DS ops are in-order: safe to overwrite after inner reads
        if (tile + 1 < NT) store_lds();
    }
}

// ---------------- Fallback: monolithic kernel (correct, slower) -------------
__launch_bounds__(256, 1)
__global__ void neuralstack_kernel(const float* __restrict__ x,
                                   const float* __restrict__ should_pop,
                                   const float* __restrict__ sharpen_ptr,
                                   const float* __restrict__ latch_enable,
                                   const float* __restrict__ latch_init,
                                   float* __restrict__ out,
                                   int T) {
    const int b = blockIdx.x;
    const int tid = threadIdx.x;
    const int wave = tid >> 6;
    const int lane = tid & 63;
    __shared__ float red[2][16];
    const float sp_d = should_pop[tid];
    const float le_d = latch_enable[tid];
    const float sharpen = sharpen_ptr[0];
    float latch = latch_init[(size_t)b * DDIM + tid];
    float a0 = sp_d * sp_d, a1 = le_d * le_d;
#pragma unroll
    for (int off = 32; off >= 1; off >>= 1) {
        a0 += __shfl_xor(a0, off, 64);
        a1 += __shfl_xor(a1, off, 64);
    }
    if (lane == 0) { red[0][wave * 4] = a0; red[0][wave * 4 + 1] = a1; }
    __syncthreads();
    const float an_sp = fmaxf(sqrtf(red[0][0] + red[0][4] + red[0][8] + red[0][12]), EPSC);
    const float an_le = fmaxf(sqrtf(red[0][1] + red[0][5] + red[0][9] + red[0][13]), EPSC);
    __syncthreads();
    float st[NSTK], ptr[NSTK];
#pragma unroll
    for (int n = 0; n < NSTK; n++) { st[n] = ZO; ptr[n] = (n == 0) ? 1.0f : ZO; }
    const float* xb = x + (size_t)b * T * DDIM + tid;
    float* ob = out + (size_t)b * T * DDIM + tid;
    const bool sharp5 = (sharpen == 5.0f);
    float inp = xb[0];
    for (int t = 0; t < T; t++) {
        const int tn = (t + 1 < T) ? (t + 1) : (T - 1);
        const float inp_next = xb[(size_t)tn * DDIM];
        float r0 = sp_d * latch, r1 = latch * latch, r2 = le_d * inp, r3 = inp * inp;
#pragma unroll
        for (int off = 32; off >= 1; off >>= 1) {
            r0 += __shfl_xor(r0, off, 64);
            r1 += __shfl_xor(r1, off, 64);
            r2 += __shfl_xor(r2, off, 64);
            r3 += __shfl_xor(r3, off, 64);
        }
        const int buf = t & 1;
        if (lane == 0) {
            red[buf][wave * 4] = r0; red[buf][wave * 4 + 1] = r1;
            red[buf][wave * 4 + 2] = r2; red[buf][wave * 4 + 3] = r3;
        }
        __syncthreads();
        const float s0 = red[buf][0] + red[buf][4] + red[buf][8] + red[buf][12];
        const float s1 = red[buf][1] + red[buf][5] + red[buf][9] + red[buf][13];
        const float s2 = red[buf][2] + red[buf][6] + red[buf][10] + red[buf][14];
        const float s3 = red[buf][3] + red[buf][7] + red[buf][11] + red[buf][15];
        const float pop = elu_f(s0 / (an_sp * fmaxf(sqrtf(s1), EPSC)));
        const float push = 1.0f - pop;
        const float g = elu_f(s2 / (an_le * fmaxf(sqrtf(s3), EPSC)));
        float q[NSTK];
#pragma unroll
        for (int n = 0; n < NSTK; n++) {
            const float pp = ptr[(n + NSTK - 1) & (NSTK - 1)];
            const float pn = ptr[(n + 1) & (NSTK - 1)];
            q[n] = fmaxf(push * pp + pop * pn, PEPS);
        }
        if (sharp5) {
#pragma unroll
            for (int n = 0; n < NSTK; n++) { const float v = q[n], v2 = v * v; q[n] = v2 * v2 * v; }
        } else {
#pragma unroll
            for (int n = 0; n < NSTK; n++) q[n] = exp2f(sharpen * log2f(q[n]));
        }
        float qa = 0.f, qb = 0.f, qc = 0.f, qd = 0.f;
#pragma unroll
        for (int n = 0; n < NSTK; n += 4) { qa += q[n]; qb += q[n+1]; qc += q[n+2]; qd += q[n+3]; }
        const float inv = 1.0f / fmaxf((qa + qb) + (qc + qd), EPSC);
        float sacc = 0.f;
#pragma unroll
        for (int n = 0; n < NSTK; n++) {
            const float pp = ptr[(n + NSTK - 1) & (NSTK - 1)];
            const float pc_ = ptr[n];
            const float ns = push * (st[n] + pp * (inp - st[n])) + pop * (st[n] + pc_ * (ZO - st[n]));
            st[n] = ns;
            sacc += ns * (q[n] * inv);
        }
#pragma unroll
        for (int n = 0; n < NSTK; n++) ptr[n] = q[n] * inv;
        ob[(size_t)t * DDIM] = pop * sacc;
        latch = fmaf(g, inp - latch, latch);
        inp = inp_next;
    }
}

extern "C" void kernel_launch(void* const* d_in, const int* in_sizes, int n_in,
                              void* d_out, int out_size, void* d_ws, size_t ws_size,
                              hipStream_t stream) {
    const float* x = (const float*)d_in[0];
    const float* should_pop = (const float*)d_in[1];
    const float* sharpen_ptr = (const float*)d_in[2];
    const float* latch_enable = (const float*)d_in[3];
    const float* latch_init = (const float*)d_in[4];
    float* out = (float*)d_out;

    const int D = in_sizes[1];                 // 256
    const int B = in_sizes[4] / D;             // 128
    const int T = in_sizes[0] / in_sizes[4];   // 256
    (void)n_in; (void)out_size;

    const size_t BT = (size_t)B * T;
    const size_t off_g = 0;
    const size_t off_pop = BT;
    const size_t off_L = 2 * BT;
    const size_t off_P = off_L + BT * D;
    const size_t need_floats = off_P + BT * 32;

    if (ws_size < need_floats * sizeof(float) || D != DDIM ||
        (T % TTILE) != 0 || (B % 2) != 0 || T > MAXT) {
        neuralstack_kernel<<<B, 256, 0, stream>>>(x, should_pop, sharpen_ptr,
                                                  latch_enable, latch_init, out, T);
        return;
    }

    float* ws = (float*)d_ws;
    float* g = ws + off_g;
    float* pop = ws + off_pop;
    float* L = ws + off_L;
    float* P = ws + off_P;

    gate4_kernel<<<dim3(T / 4, B), 256, 0, stream>>>(x, latch_enable, g, T);
    latch_scan_kernel<<<B * 4, 64, 0, stream>>>(x, latch_init, g, L, T);
    gate4_kernel<<<dim3(T / 4, B), 256, 0, stream>>>(L, should_pop, pop, T);
    ptr_scan_kernel<<<B / 2, 64, 0, stream>>>(pop, sharpen_ptr, P, T);
    stack_kernel<<<dim3(D / 8, B), 64, 0, stream>>>(x, P, pop, out, T);
}